// Round 8
// baseline (1345.825 us; speedup 1.0000x reference)
//
#include <hip/hip_runtime.h>
#include <math.h>

#define NN 50000
#define EE 1600000
#define ETOT (EE + NN)

__device__ __forceinline__ float lrelu(float x){ return x > 0.f ? x : 0.2f * x; }
__device__ __forceinline__ float sigmoidf_(float x){ return 1.f / (1.f + __expf(-x)); }

template<int RW>
__device__ __forceinline__ float rsum(float v){
  #pragma unroll
  for (int m = RW >> 1; m > 0; m >>= 1) v += __shfl_xor(v, m, RW);
  return v;
}

// ---------------- CSR build ----------------
__global__ void k_hist(const int* __restrict__ ei, int* __restrict__ deg){
  int i = blockIdx.x * blockDim.x + threadIdx.x;
  if (i >= ETOT) return;
  int dst = (i < EE) ? ei[EE + i] : (i - EE);
  atomicAdd(&deg[dst], 1);
}

__global__ void k_blockscan(const int* __restrict__ deg, int* __restrict__ partial, int* __restrict__ spine){
  __shared__ int s[256];
  int t = threadIdx.x;
  int i = blockIdx.x * 256 + t;
  int v = (i < NN) ? deg[i] : 0;
  s[t] = v; __syncthreads();
  for (int off = 1; off < 256; off <<= 1){
    int x = (t >= off) ? s[t - off] : 0; __syncthreads();
    s[t] += x; __syncthreads();
  }
  if (i < NN) partial[i] = s[t] - v;           // exclusive within block
  if (t == 255) spine[blockIdx.x] = s[255];    // block total
}

__global__ void k_spinescan(int* __restrict__ spine, int nb){
  __shared__ int s[256];
  int t = threadIdx.x;
  int v = (t < nb) ? spine[t] : 0;
  s[t] = v; __syncthreads();
  for (int off = 1; off < 256; off <<= 1){
    int x = (t >= off) ? s[t - off] : 0; __syncthreads();
    s[t] += x; __syncthreads();
  }
  if (t < nb) spine[t] = s[t] - v;             // exclusive
}

__global__ void k_finalize(int* __restrict__ cur, const int* __restrict__ spine, int* __restrict__ off){
  int i = blockIdx.x * 256 + threadIdx.x;
  if (i > NN) return;
  if (i == NN){ off[NN] = ETOT; return; }
  int v = cur[i] + spine[i >> 8];
  off[i] = v;
  cur[i] = v;                                  // scatter cursor
}

__global__ void k_scatter(const int* __restrict__ ei, int* __restrict__ cur, int* __restrict__ srcs){
  int i = blockIdx.x * blockDim.x + threadIdx.x;
  if (i >= ETOT) return;
  int src, dst;
  if (i < EE){ src = ei[i]; dst = ei[EE + i]; }
  else       { src = i - EE; dst = src; }
  int pos = atomicAdd(&cur[dst], 1);
  srcs[pos] = src;
}

// ---------------- fused linear (GEMV over nodes) ----------------
// out[n][c] = sum_k in[n][k] * W[k][c]  (+ b1 + b2)
// in is concat(A (stride F1), B (stride F-F1, optionally gathered via idxB)).
// If WANT_AL: also write alS[n][h] = sum_c out*asrc[c], alD likewise (pre-bias; b1/b2 null for GAT).
template<int F, int F1, int O, int C, bool WANT_AL>
__global__ void k_linear(const float* __restrict__ A, const float* __restrict__ B, const int* __restrict__ idxB,
                         const float* __restrict__ W, const float* __restrict__ b1, const float* __restrict__ b2,
                         const float* __restrict__ asrc, const float* __restrict__ adst,
                         float* __restrict__ out, float* __restrict__ alS, float* __restrict__ alD)
{
  constexpr int KC  = 32;
  constexpr int CPL = O / 64;        // cols per lane: 1, 2 or 4
  constexpr int NPB = 16, NPW = 4;
  constexpr int HH  = O / C;         // heads (when WANT_AL)
  constexpr int RW  = C / (CPL > 2 ? 2 : CPL); // reduce width (unused for CPL==4)

  __shared__ float Ws[KC][O];
  __shared__ float xs[NPB][KC];

  const int tid  = threadIdx.x;
  const int wave = tid >> 6, lane = tid & 63;
  const int nb   = blockIdx.x * NPB;

  float acc[NPW][CPL];
  #pragma unroll
  for (int j = 0; j < NPW; ++j)
    #pragma unroll
    for (int i = 0; i < CPL; ++i) acc[j][i] = 0.f;

  constexpr int NCHUNK = F / KC;
  for (int ch = 0; ch < NCHUNK; ++ch){
    const int kc0 = ch * KC;
    // stage W chunk (contiguous rows) via float4
    const float4* w4  = reinterpret_cast<const float4*>(W + (size_t)kc0 * O);
    float4*       ws4 = reinterpret_cast<float4*>(&Ws[0][0]);
    #pragma unroll
    for (int r = 0; r < (KC * O) / 1024; ++r) ws4[tid + r * 256] = w4[tid + r * 256];
    // stage inputs for NPB nodes
    #pragma unroll
    for (int r = 0; r < (NPB * KC) / 256; ++r){
      int idx = tid + r * 256;
      int ln = idx >> 5, k = idx & 31;
      int n = nb + ln;
      float v = 0.f;
      if (n < NN){
        int kg = kc0 + k;
        if (kg < F1) v = A[(size_t)n * F1 + kg];
        else {
          int n2 = idxB ? idxB[n] : n;
          v = B[(size_t)n2 * (F - F1) + (kg - F1)];
        }
      }
      xs[ln][k] = v;
    }
    __syncthreads();

    #pragma unroll
    for (int k = 0; k < KC; ++k){
      if constexpr (CPL == 1){
        float wv = Ws[k][lane];
        #pragma unroll
        for (int j = 0; j < NPW; ++j)
          acc[j][0] = fmaf(xs[wave * NPW + j][k], wv, acc[j][0]);
      } else if constexpr (CPL == 2){
        float2 wv = *(const float2*)&Ws[k][2 * lane];
        #pragma unroll
        for (int j = 0; j < NPW; ++j){
          float xk = xs[wave * NPW + j][k];
          acc[j][0] = fmaf(xk, wv.x, acc[j][0]);
          acc[j][1] = fmaf(xk, wv.y, acc[j][1]);
        }
      } else {
        float2 w0 = *(const float2*)&Ws[k][2 * lane];
        float2 w1 = *(const float2*)&Ws[k][128 + 2 * lane];
        #pragma unroll
        for (int j = 0; j < NPW; ++j){
          float xk = xs[wave * NPW + j][k];
          acc[j][0] = fmaf(xk, w0.x, acc[j][0]);
          acc[j][1] = fmaf(xk, w0.y, acc[j][1]);
          acc[j][2] = fmaf(xk, w1.x, acc[j][2]);
          acc[j][3] = fmaf(xk, w1.y, acc[j][3]);
        }
      }
    }
    __syncthreads();
  }

  // epilogue
  #pragma unroll
  for (int j = 0; j < NPW; ++j){
    int n = nb + wave * NPW + j;
    if (n >= NN) continue;
    if constexpr (CPL == 1){
      float v = acc[j][0];
      if (b1) v += b1[lane];
      if (b2) v += b2[lane];
      out[(size_t)n * O + lane] = v;
      if constexpr (WANT_AL){
        float ps = rsum<RW>(v * asrc[lane]);
        float pd = rsum<RW>(v * adst[lane]);
        if (lane == 0){ alS[n] = ps; alD[n] = pd; }
      }
    } else if constexpr (CPL == 2){
      int c0 = 2 * lane;
      float v0 = acc[j][0], v1 = acc[j][1];
      if (b1){ v0 += b1[c0]; v1 += b1[c0 + 1]; }
      if (b2){ v0 += b2[c0]; v1 += b2[c0 + 1]; }
      *(float2*)(out + (size_t)n * O + c0) = make_float2(v0, v1);
      if constexpr (WANT_AL){
        float ps = rsum<RW>(v0 * asrc[c0] + v1 * asrc[c0 + 1]);
        float pd = rsum<RW>(v0 * adst[c0] + v1 * adst[c0 + 1]);
        if ((lane & (RW - 1)) == 0){
          int h = lane / RW;
          alS[(size_t)n * HH + h] = ps;
          alD[(size_t)n * HH + h] = pd;
        }
      }
    } else {
      int c0 = 2 * lane, c1 = 128 + 2 * lane;
      float v0 = acc[j][0], v1 = acc[j][1], v2 = acc[j][2], v3 = acc[j][3];
      if (b1){ v0 += b1[c0]; v1 += b1[c0 + 1]; v2 += b1[c1]; v3 += b1[c1 + 1]; }
      if (b2){ v0 += b2[c0]; v1 += b2[c0 + 1]; v2 += b2[c1]; v3 += b2[c1 + 1]; }
      *(float2*)(out + (size_t)n * O + c0) = make_float2(v0, v1);
      *(float2*)(out + (size_t)n * O + c1) = make_float2(v2, v3);
    }
  }
}

// ---------------- GAT aggregation (wave per dst node) ----------------
template<int O, bool ELU>
__global__ void k_aggregate(const int* __restrict__ off, const int* __restrict__ srcs,
                            const float* __restrict__ xw, const float* __restrict__ alS,
                            const float* __restrict__ alD, const float* __restrict__ bias,
                            float* __restrict__ out)
{
  constexpr int CPL = O / 64;
  constexpr int H   = (O == 128) ? 4 : 1;
  const int wave = threadIdx.x >> 6, lane = threadIdx.x & 63;
  const int n = blockIdx.x * 4 + wave;
  if (n >= NN) return;
  const int h = (O == 128) ? (lane >> 4) : 0;   // c = 2*lane -> head = lane/16
  const float ad = alD[(size_t)n * H + h];
  const int s0 = off[n], s1 = off[n + 1];

  float m = -3.4e38f;
  for (int t = s0; t < s1; ++t){
    int s = srcs[t];
    float a = lrelu(alS[(size_t)s * H + h] + ad);
    m = fmaxf(m, a);
  }
  float den = 0.f, accx = 0.f, accy = 0.f;
  for (int t = s0; t < s1; ++t){
    int s = srcs[t];
    float a = lrelu(alS[(size_t)s * H + h] + ad);
    float ex = __expf(a - m);
    den += ex;
    if constexpr (CPL == 2){
      float2 wv = *(const float2*)&xw[(size_t)s * O + 2 * lane];
      accx = fmaf(ex, wv.x, accx);
      accy = fmaf(ex, wv.y, accy);
    } else {
      accx = fmaf(ex, xw[(size_t)s * O + lane], accx);
    }
  }
  float inv = 1.f / (den + 1e-16f);
  if constexpr (CPL == 2){
    float o0 = accx * inv + bias[2 * lane];
    float o1 = accy * inv + bias[2 * lane + 1];
    if (ELU){ o0 = o0 > 0.f ? o0 : expm1f(o0); o1 = o1 > 0.f ? o1 : expm1f(o1); }
    *(float2*)(out + (size_t)n * O + 2 * lane) = make_float2(o0, o1);
  } else {
    float o0 = accx * inv + bias[lane];
    if (ELU) o0 = o0 > 0.f ? o0 : expm1f(o0);
    out[(size_t)n * O + lane] = o0;
  }
}

// ---------------- LSTM weight concat+transpose: Wt[k][r] ----------------
__global__ void k_wcat(const float* __restrict__ Wih, const float* __restrict__ Whh, float* __restrict__ Wt){
  int i = blockIdx.x * 256 + threadIdx.x;   // over 128*256
  if (i >= 128 * 256) return;
  int k = i >> 8, r = i & 255;
  Wt[i] = (k < 64) ? Wih[r * 64 + k] : Whh[r * 64 + (k - 64)];
}

// ---------------- LSTM elementwise (+ optional final projection) ----------------
__global__ void k_lstm(const float* __restrict__ gates, const float* __restrict__ c_full_l,
                       const int* __restrict__ nid,
                       float* __restrict__ h_out, float* __restrict__ c_out,
                       float* __restrict__ h_next,
                       const float* __restrict__ outW, const float* __restrict__ outb,
                       float* __restrict__ pred)
{
  int tid = blockIdx.x * blockDim.x + threadIdx.x;
  int n = tid >> 6, j = tid & 63;
  if (n >= NN) return;
  const float* g = gates + (size_t)n * 256;
  float i_ = sigmoidf_(g[j]);
  float f_ = sigmoidf_(g[64 + j]);
  float g_ = tanhf(g[128 + j]);
  float o_ = sigmoidf_(g[192 + j]);
  int n2 = nid ? nid[n] : n;
  float c0 = c_full_l[(size_t)n2 * 64 + j];
  float cn = fmaf(f_, c0, i_ * g_);
  float hn = o_ * tanhf(cn);
  c_out[(size_t)n * 64 + j] = cn;
  h_out[(size_t)n * 64 + j] = hn;
  if (h_next) h_next[(size_t)n * 64 + j] = hn;
  if (pred){
    float v = hn * outW[j];
    #pragma unroll
    for (int m = 32; m > 0; m >>= 1) v += __shfl_xor(v, m, 64);
    if (j == 0) pred[n] = v + outb[0];
  }
}

extern "C" void kernel_launch(void* const* d_in, const int* in_sizes, int n_in,
                              void* d_out, int out_size, void* d_ws, size_t ws_size,
                              hipStream_t stream)
{
  const float* x      = (const float*)d_in[0];
  const int*   ei     = (const int*)  d_in[1];
  const int*   nid    = (const int*)  d_in[3];
  const float* h_full = (const float*)d_in[4];
  const float* c_full = (const float*)d_in[5];
  const float* W0   = (const float*)d_in[6];
  const float* as0  = (const float*)d_in[7];
  const float* ad0  = (const float*)d_in[8];
  const float* b0   = (const float*)d_in[9];
  const float* W1   = (const float*)d_in[10];
  const float* as1  = (const float*)d_in[11];
  const float* ad1  = (const float*)d_in[12];
  const float* b1   = (const float*)d_in[13];
  const float* W2   = (const float*)d_in[14];
  const float* as2  = (const float*)d_in[15];
  const float* ad2  = (const float*)d_in[16];
  const float* b2   = (const float*)d_in[17];
  const float* Wih0 = (const float*)d_in[18];
  const float* Whh0 = (const float*)d_in[19];
  const float* bih0 = (const float*)d_in[20];
  const float* bhh0 = (const float*)d_in[21];
  const float* Wih1 = (const float*)d_in[22];
  const float* Whh1 = (const float*)d_in[23];
  const float* bih1 = (const float*)d_in[24];
  const float* bhh1 = (const float*)d_in[25];
  const float* outW = (const float*)d_in[26];
  const float* outb = (const float*)d_in[27];
  float* out = (float*)d_out;

  char* ws = (char*)d_ws;
  size_t o = 0;
  auto take = [&](size_t bytes) -> char* {
    char* p = ws + o;
    o = (o + bytes + 255) & ~(size_t)255;
    return p;
  };
  int*   off   = (int*)  take((NN + 1) * sizeof(int));
  int*   cur   = (int*)  take((size_t)NN * sizeof(int));
  int*   srcs  = (int*)  take((size_t)ETOT * sizeof(int));
  int*   spine = (int*)  take(256 * sizeof(int));
  float* bufA  = (float*)take((size_t)NN * 128 * sizeof(float));
  float* bufB  = (float*)take((size_t)NN * 128 * sizeof(float));
  float* alS   = (float*)take((size_t)NN * 4 * sizeof(float));
  float* alD   = (float*)take((size_t)NN * 4 * sizeof(float));
  float* gates = (float*)take((size_t)NN * 256 * sizeof(float));
  float* Wt0   = (float*)take(128 * 256 * sizeof(float));
  float* Wt1   = (float*)take(128 * 256 * sizeof(float));
  (void)ws_size; (void)n_in; (void)in_sizes; (void)out_size;

  const int NB_SCAN = (NN + 255) / 256;                 // 196
  // ---- CSR build ----
  hipMemsetAsync(off, 0, (NN + 1) * sizeof(int), stream);
  k_hist     <<<(ETOT + 255) / 256, 256, 0, stream>>>(ei, off);
  k_blockscan<<<NB_SCAN, 256, 0, stream>>>(off, cur, spine);
  k_spinescan<<<1, 256, 0, stream>>>(spine, NB_SCAN);
  k_finalize <<<NB_SCAN, 256, 0, stream>>>(cur, spine, off);
  k_scatter  <<<(ETOT + 255) / 256, 256, 0, stream>>>(ei, cur, srcs);

  const int GB_LIN = NN / 16;          // 3125
  const int GB_AGG = (NN + 3) / 4;     // 12500
  // ---- GAT layer 0 ----
  k_linear<32, 32, 128, 32, true><<<GB_LIN, 256, 0, stream>>>(
      x, nullptr, nullptr, W0, nullptr, nullptr, as0, ad0, bufA, alS, alD);
  k_aggregate<128, true><<<GB_AGG, 256, 0, stream>>>(off, srcs, bufA, alS, alD, b0, bufB);
  // ---- GAT layer 1 ----
  k_linear<128, 128, 128, 32, true><<<GB_LIN, 256, 0, stream>>>(
      bufB, nullptr, nullptr, W1, nullptr, nullptr, as1, ad1, bufA, alS, alD);
  k_aggregate<128, true><<<GB_AGG, 256, 0, stream>>>(off, srcs, bufA, alS, alD, b1, bufB);
  // ---- GAT layer 2 (H=1, C=64, no ELU) ----
  k_linear<128, 128, 64, 64, true><<<GB_LIN, 256, 0, stream>>>(
      bufB, nullptr, nullptr, W2, nullptr, nullptr, as2, ad2, bufA, alS, alD);
  k_aggregate<64, false><<<GB_AGG, 256, 0, stream>>>(off, srcs, bufA, alS, alD, b2, bufB);
  // bufB[0 : N*64] now holds g

  // ---- LSTM ----
  k_wcat<<<128, 256, 0, stream>>>(Wih0, Whh0, Wt0);
  k_wcat<<<128, 256, 0, stream>>>(Wih1, Whh1, Wt1);

  float* pred_out = out;
  float* hs_out   = out + NN;
  float* cs_out   = out + NN + 2 * (size_t)NN * 64;

  // layer 0: gates = [g, h0_0] @ Wt0 (+bih+bhh)
  k_linear<128, 64, 256, 64, false><<<GB_LIN, 256, 0, stream>>>(
      bufB, h_full + 0, nid, Wt0, bih0, bhh0, nullptr, nullptr, gates, nullptr, nullptr);
  k_lstm<<<(NN * 64) / 256, 256, 0, stream>>>(
      gates, c_full + 0, nid, hs_out, cs_out, bufA, nullptr, nullptr, nullptr);
  // layer 1: gates = [h_new0, h0_1] @ Wt1
  k_linear<128, 64, 256, 64, false><<<GB_LIN, 256, 0, stream>>>(
      bufA, h_full + (size_t)NN * 64, nid, Wt1, bih1, bhh1, nullptr, nullptr, gates, nullptr, nullptr);
  k_lstm<<<(NN * 64) / 256, 256, 0, stream>>>(
      gates, c_full + (size_t)NN * 64, nid,
      hs_out + (size_t)NN * 64, cs_out + (size_t)NN * 64, nullptr, outW, outb, pred_out);
}

// Round 13
// 1005.525 us; speedup vs baseline: 1.3384x; 1.3384x over previous
//
#include <hip/hip_runtime.h>
#include <math.h>

#define NN 50000
#define EE 1600000
#define ETOT (EE + NN)

__device__ __forceinline__ float lrelu(float x){ return x > 0.f ? x : 0.2f * x; }
__device__ __forceinline__ float sigmoidf_(float x){ return 1.f / (1.f + __expf(-x)); }

template<int RW>
__device__ __forceinline__ float rsum(float v){
  #pragma unroll
  for (int m = RW >> 1; m > 0; m >>= 1) v += __shfl_xor(v, m, RW);
  return v;
}

// ---------------- CSR build ----------------
__global__ void k_hist(const int* __restrict__ ei, int* __restrict__ deg){
  int i = blockIdx.x * blockDim.x + threadIdx.x;
  if (i >= ETOT) return;
  int dst = (i < EE) ? ei[EE + i] : (i - EE);
  atomicAdd(&deg[dst], 1);
}

__global__ void k_blockscan(const int* __restrict__ deg, int* __restrict__ partial, int* __restrict__ spine){
  __shared__ int s[256];
  int t = threadIdx.x;
  int i = blockIdx.x * 256 + t;
  int v = (i < NN) ? deg[i] : 0;
  s[t] = v; __syncthreads();
  for (int off = 1; off < 256; off <<= 1){
    int x = (t >= off) ? s[t - off] : 0; __syncthreads();
    s[t] += x; __syncthreads();
  }
  if (i < NN) partial[i] = s[t] - v;           // exclusive within block
  if (t == 255) spine[blockIdx.x] = s[255];    // block total
}

__global__ void k_spinescan(int* __restrict__ spine, int nb){
  __shared__ int s[256];
  int t = threadIdx.x;
  int v = (t < nb) ? spine[t] : 0;
  s[t] = v; __syncthreads();
  for (int off = 1; off < 256; off <<= 1){
    int x = (t >= off) ? s[t - off] : 0; __syncthreads();
    s[t] += x; __syncthreads();
  }
  if (t < nb) spine[t] = s[t] - v;             // exclusive
}

__global__ void k_finalize(int* __restrict__ cur, const int* __restrict__ spine, int* __restrict__ off){
  int i = blockIdx.x * 256 + threadIdx.x;
  if (i > NN) return;
  if (i == NN){ off[NN] = ETOT; return; }
  int v = cur[i] + spine[i >> 8];
  off[i] = v;
  cur[i] = v;                                  // scatter cursor
}

__global__ void k_scatter(const int* __restrict__ ei, int* __restrict__ cur, int* __restrict__ srcs){
  int i = blockIdx.x * blockDim.x + threadIdx.x;
  if (i >= ETOT) return;
  int src, dst;
  if (i < EE){ src = ei[i]; dst = ei[EE + i]; }
  else       { src = i - EE; dst = src; }
  int pos = atomicAdd(&cur[dst], 1);
  srcs[pos] = src;
}

// ---------------- fused linear (GEMV over nodes) ----------------
// out[n][c] = sum_k in[n][k] * W[k][c]  (+ b1 + b2)
// in is concat(A (stride F1), B (stride F-F1, optionally gathered via idxB)).
// If WANT_AL: also write alS[n][h] = sum_c out*asrc[c], alD likewise (pre-bias; b1/b2 null for GAT).
template<int F, int F1, int O, int C, bool WANT_AL>
__global__ void k_linear(const float* __restrict__ A, const float* __restrict__ B, const int* __restrict__ idxB,
                         const float* __restrict__ W, const float* __restrict__ b1, const float* __restrict__ b2,
                         const float* __restrict__ asrc, const float* __restrict__ adst,
                         float* __restrict__ out, float* __restrict__ alS, float* __restrict__ alD)
{
  constexpr int KC  = 32;
  constexpr int CPL = O / 64;        // cols per lane: 1, 2 or 4
  constexpr int NPB = 16, NPW = 4;
  constexpr int HH  = O / C;         // heads (when WANT_AL)
  constexpr int RW  = C / (CPL > 2 ? 2 : CPL); // reduce width (unused for CPL==4)

  __shared__ float Ws[KC][O];
  __shared__ float xs[NPB][KC];

  const int tid  = threadIdx.x;
  const int wave = tid >> 6, lane = tid & 63;
  const int nb   = blockIdx.x * NPB;

  float acc[NPW][CPL];
  #pragma unroll
  for (int j = 0; j < NPW; ++j)
    #pragma unroll
    for (int i = 0; i < CPL; ++i) acc[j][i] = 0.f;

  constexpr int NCHUNK = F / KC;
  for (int ch = 0; ch < NCHUNK; ++ch){
    const int kc0 = ch * KC;
    // stage W chunk (contiguous rows) via float4
    const float4* w4  = reinterpret_cast<const float4*>(W + (size_t)kc0 * O);
    float4*       ws4 = reinterpret_cast<float4*>(&Ws[0][0]);
    #pragma unroll
    for (int r = 0; r < (KC * O) / 1024; ++r) ws4[tid + r * 256] = w4[tid + r * 256];
    // stage inputs for NPB nodes
    #pragma unroll
    for (int r = 0; r < (NPB * KC) / 256; ++r){
      int idx = tid + r * 256;
      int ln = idx >> 5, k = idx & 31;
      int n = nb + ln;
      float v = 0.f;
      if (n < NN){
        int kg = kc0 + k;
        if (kg < F1) v = A[(size_t)n * F1 + kg];
        else {
          int n2 = idxB ? idxB[n] : n;
          v = B[(size_t)n2 * (F - F1) + (kg - F1)];
        }
      }
      xs[ln][k] = v;
    }
    __syncthreads();

    #pragma unroll
    for (int k = 0; k < KC; ++k){
      if constexpr (CPL == 1){
        float wv = Ws[k][lane];
        #pragma unroll
        for (int j = 0; j < NPW; ++j)
          acc[j][0] = fmaf(xs[wave * NPW + j][k], wv, acc[j][0]);
      } else if constexpr (CPL == 2){
        float2 wv = *(const float2*)&Ws[k][2 * lane];
        #pragma unroll
        for (int j = 0; j < NPW; ++j){
          float xk = xs[wave * NPW + j][k];
          acc[j][0] = fmaf(xk, wv.x, acc[j][0]);
          acc[j][1] = fmaf(xk, wv.y, acc[j][1]);
        }
      } else {
        float2 w0 = *(const float2*)&Ws[k][2 * lane];
        float2 w1 = *(const float2*)&Ws[k][128 + 2 * lane];
        #pragma unroll
        for (int j = 0; j < NPW; ++j){
          float xk = xs[wave * NPW + j][k];
          acc[j][0] = fmaf(xk, w0.x, acc[j][0]);
          acc[j][1] = fmaf(xk, w0.y, acc[j][1]);
          acc[j][2] = fmaf(xk, w1.x, acc[j][2]);
          acc[j][3] = fmaf(xk, w1.y, acc[j][3]);
        }
      }
    }
    __syncthreads();
  }

  // epilogue
  #pragma unroll
  for (int j = 0; j < NPW; ++j){
    int n = nb + wave * NPW + j;
    if (n >= NN) continue;
    if constexpr (CPL == 1){
      float v = acc[j][0];
      if (b1) v += b1[lane];
      if (b2) v += b2[lane];
      out[(size_t)n * O + lane] = v;
      if constexpr (WANT_AL){
        float ps = rsum<RW>(v * asrc[lane]);
        float pd = rsum<RW>(v * adst[lane]);
        if (lane == 0){ alS[n] = ps; alD[n] = pd; }
      }
    } else if constexpr (CPL == 2){
      int c0 = 2 * lane;
      float v0 = acc[j][0], v1 = acc[j][1];
      if (b1){ v0 += b1[c0]; v1 += b1[c0 + 1]; }
      if (b2){ v0 += b2[c0]; v1 += b2[c0 + 1]; }
      *(float2*)(out + (size_t)n * O + c0) = make_float2(v0, v1);
      if constexpr (WANT_AL){
        float ps = rsum<RW>(v0 * asrc[c0] + v1 * asrc[c0 + 1]);
        float pd = rsum<RW>(v0 * adst[c0] + v1 * adst[c0 + 1]);
        if ((lane & (RW - 1)) == 0){
          int h = lane / RW;
          alS[(size_t)n * HH + h] = ps;
          alD[(size_t)n * HH + h] = pd;
        }
      }
    } else {
      int c0 = 2 * lane, c1 = 128 + 2 * lane;
      float v0 = acc[j][0], v1 = acc[j][1], v2 = acc[j][2], v3 = acc[j][3];
      if (b1){ v0 += b1[c0]; v1 += b1[c0 + 1]; v2 += b1[c1]; v3 += b1[c1 + 1]; }
      if (b2){ v0 += b2[c0]; v1 += b2[c0 + 1]; v2 += b2[c1]; v3 += b2[c1 + 1]; }
      *(float2*)(out + (size_t)n * O + c0) = make_float2(v0, v1);
      *(float2*)(out + (size_t)n * O + c1) = make_float2(v2, v3);
    }
  }
}

// ---------------- GAT aggregation (wave per dst node, online softmax) ----------------
// Single pass: running max m, denominator den, accumulators rescaled branchlessly.
// srcs indices prefetched 64-at-a-time via one coalesced load + __shfl broadcast,
// removing one level from the per-edge dependent-load chain (was: uniform srcs load
// -> gather; now: register shfl -> gather).
template<int O, bool ELU>
__global__ void k_aggregate(const int* __restrict__ off, const int* __restrict__ srcs,
                            const float* __restrict__ xw, const float* __restrict__ alS,
                            const float* __restrict__ alD, const float* __restrict__ bias,
                            float* __restrict__ out)
{
  constexpr int CPL = O / 64;
  constexpr int H   = (O == 128) ? 4 : 1;
  const int wave = threadIdx.x >> 6, lane = threadIdx.x & 63;
  const int n = blockIdx.x * 4 + wave;
  if (n >= NN) return;
  const int h = (O == 128) ? (lane >> 4) : 0;   // c = 2*lane -> head = lane/16
  const float ad = alD[(size_t)n * H + h];
  const int s0 = off[n], s1 = off[n + 1];

  float m = -3.4e38f, den = 0.f, accx = 0.f, accy = 0.f;
  for (int base = s0; base < s1; base += 64){
    int idx = base + lane;
    int sv = (idx < s1) ? srcs[idx] : 0;        // one coalesced load: 64 indices
    int cnt = s1 - base; if (cnt > 64) cnt = 64;
    #pragma unroll 4
    for (int u = 0; u < cnt; ++u){
      int s = __shfl(sv, u, 64);                // register-only broadcast
      float a = lrelu(alS[(size_t)s * H + h] + ad);
      float mn = fmaxf(m, a);
      float sc = __expf(m - mn);                // 1 when no new max; 0 on first edge
      float ex = __expf(a - mn);
      if constexpr (CPL == 2){
        float2 wv = *(const float2*)&xw[(size_t)s * O + 2 * lane];
        accx = accx * sc + ex * wv.x;
        accy = accy * sc + ex * wv.y;
      } else {
        accx = accx * sc + ex * xw[(size_t)s * O + lane];
      }
      den = den * sc + ex;
      m = mn;
    }
  }
  float inv = 1.f / (den + 1e-16f);
  if constexpr (CPL == 2){
    float o0 = accx * inv + bias[2 * lane];
    float o1 = accy * inv + bias[2 * lane + 1];
    if (ELU){ o0 = o0 > 0.f ? o0 : expm1f(o0); o1 = o1 > 0.f ? o1 : expm1f(o1); }
    *(float2*)(out + (size_t)n * O + 2 * lane) = make_float2(o0, o1);
  } else {
    float o0 = accx * inv + bias[lane];
    if (ELU) o0 = o0 > 0.f ? o0 : expm1f(o0);
    out[(size_t)n * O + lane] = o0;
  }
}

// ---------------- LSTM weight concat+transpose: Wt[k][r] ----------------
__global__ void k_wcat(const float* __restrict__ Wih, const float* __restrict__ Whh, float* __restrict__ Wt){
  int i = blockIdx.x * 256 + threadIdx.x;   // over 128*256
  if (i >= 128 * 256) return;
  int k = i >> 8, r = i & 255;
  Wt[i] = (k < 64) ? Wih[r * 64 + k] : Whh[r * 64 + (k - 64)];
}

// ---------------- LSTM elementwise (+ optional final projection) ----------------
__global__ void k_lstm(const float* __restrict__ gates, const float* __restrict__ c_full_l,
                       const int* __restrict__ nid,
                       float* __restrict__ h_out, float* __restrict__ c_out,
                       float* __restrict__ h_next,
                       const float* __restrict__ outW, const float* __restrict__ outb,
                       float* __restrict__ pred)
{
  int tid = blockIdx.x * blockDim.x + threadIdx.x;
  int n = tid >> 6, j = tid & 63;
  if (n >= NN) return;
  const float* g = gates + (size_t)n * 256;
  float i_ = sigmoidf_(g[j]);
  float f_ = sigmoidf_(g[64 + j]);
  float g_ = tanhf(g[128 + j]);
  float o_ = sigmoidf_(g[192 + j]);
  int n2 = nid ? nid[n] : n;
  float c0 = c_full_l[(size_t)n2 * 64 + j];
  float cn = fmaf(f_, c0, i_ * g_);
  float hn = o_ * tanhf(cn);
  c_out[(size_t)n * 64 + j] = cn;
  h_out[(size_t)n * 64 + j] = hn;
  if (h_next) h_next[(size_t)n * 64 + j] = hn;
  if (pred){
    float v = hn * outW[j];
    #pragma unroll
    for (int m = 32; m > 0; m >>= 1) v += __shfl_xor(v, m, 64);
    if (j == 0) pred[n] = v + outb[0];
  }
}

extern "C" void kernel_launch(void* const* d_in, const int* in_sizes, int n_in,
                              void* d_out, int out_size, void* d_ws, size_t ws_size,
                              hipStream_t stream)
{
  const float* x      = (const float*)d_in[0];
  const int*   ei     = (const int*)  d_in[1];
  const int*   nid    = (const int*)  d_in[3];
  const float* h_full = (const float*)d_in[4];
  const float* c_full = (const float*)d_in[5];
  const float* W0   = (const float*)d_in[6];
  const float* as0  = (const float*)d_in[7];
  const float* ad0  = (const float*)d_in[8];
  const float* b0   = (const float*)d_in[9];
  const float* W1   = (const float*)d_in[10];
  const float* as1  = (const float*)d_in[11];
  const float* ad1  = (const float*)d_in[12];
  const float* b1   = (const float*)d_in[13];
  const float* W2   = (const float*)d_in[14];
  const float* as2  = (const float*)d_in[15];
  const float* ad2  = (const float*)d_in[16];
  const float* b2   = (const float*)d_in[17];
  const float* Wih0 = (const float*)d_in[18];
  const float* Whh0 = (const float*)d_in[19];
  const float* bih0 = (const float*)d_in[20];
  const float* bhh0 = (const float*)d_in[21];
  const float* Wih1 = (const float*)d_in[22];
  const float* Whh1 = (const float*)d_in[23];
  const float* bih1 = (const float*)d_in[24];
  const float* bhh1 = (const float*)d_in[25];
  const float* outW = (const float*)d_in[26];
  const float* outb = (const float*)d_in[27];
  float* out = (float*)d_out;

  char* ws = (char*)d_ws;
  size_t o = 0;
  auto take = [&](size_t bytes) -> char* {
    char* p = ws + o;
    o = (o + bytes + 255) & ~(size_t)255;
    return p;
  };
  int*   off   = (int*)  take((NN + 1) * sizeof(int));
  int*   cur   = (int*)  take((size_t)NN * sizeof(int));
  int*   srcs  = (int*)  take((size_t)ETOT * sizeof(int));
  int*   spine = (int*)  take(256 * sizeof(int));
  float* bufA  = (float*)take((size_t)NN * 128 * sizeof(float));
  float* bufB  = (float*)take((size_t)NN * 128 * sizeof(float));
  float* alS   = (float*)take((size_t)NN * 4 * sizeof(float));
  float* alD   = (float*)take((size_t)NN * 4 * sizeof(float));
  float* gates = (float*)take((size_t)NN * 256 * sizeof(float));
  float* Wt0   = (float*)take(128 * 256 * sizeof(float));
  float* Wt1   = (float*)take(128 * 256 * sizeof(float));
  (void)ws_size; (void)n_in; (void)in_sizes; (void)out_size;

  const int NB_SCAN = (NN + 255) / 256;                 // 196
  // ---- CSR build ----
  hipMemsetAsync(off, 0, (NN + 1) * sizeof(int), stream);
  k_hist     <<<(ETOT + 255) / 256, 256, 0, stream>>>(ei, off);
  k_blockscan<<<NB_SCAN, 256, 0, stream>>>(off, cur, spine);
  k_spinescan<<<1, 256, 0, stream>>>(spine, NB_SCAN);
  k_finalize <<<NB_SCAN, 256, 0, stream>>>(cur, spine, off);
  k_scatter  <<<(ETOT + 255) / 256, 256, 0, stream>>>(ei, cur, srcs);

  const int GB_LIN = NN / 16;          // 3125
  const int GB_AGG = (NN + 3) / 4;     // 12500
  // ---- GAT layer 0 ----
  k_linear<32, 32, 128, 32, true><<<GB_LIN, 256, 0, stream>>>(
      x, nullptr, nullptr, W0, nullptr, nullptr, as0, ad0, bufA, alS, alD);
  k_aggregate<128, true><<<GB_AGG, 256, 0, stream>>>(off, srcs, bufA, alS, alD, b0, bufB);
  // ---- GAT layer 1 ----
  k_linear<128, 128, 128, 32, true><<<GB_LIN, 256, 0, stream>>>(
      bufB, nullptr, nullptr, W1, nullptr, nullptr, as1, ad1, bufA, alS, alD);
  k_aggregate<128, true><<<GB_AGG, 256, 0, stream>>>(off, srcs, bufA, alS, alD, b1, bufB);
  // ---- GAT layer 2 (H=1, C=64, no ELU) ----
  k_linear<128, 128, 64, 64, true><<<GB_LIN, 256, 0, stream>>>(
      bufB, nullptr, nullptr, W2, nullptr, nullptr, as2, ad2, bufA, alS, alD);
  k_aggregate<64, false><<<GB_AGG, 256, 0, stream>>>(off, srcs, bufA, alS, alD, b2, bufB);
  // bufB[0 : N*64] now holds g

  // ---- LSTM ----
  k_wcat<<<128, 256, 0, stream>>>(Wih0, Whh0, Wt0);
  k_wcat<<<128, 256, 0, stream>>>(Wih1, Whh1, Wt1);

  float* pred_out = out;
  float* hs_out   = out + NN;
  float* cs_out   = out + NN + 2 * (size_t)NN * 64;

  // layer 0: gates = [g, h0_0] @ Wt0 (+bih+bhh)
  k_linear<128, 64, 256, 64, false><<<GB_LIN, 256, 0, stream>>>(
      bufB, h_full + 0, nid, Wt0, bih0, bhh0, nullptr, nullptr, gates, nullptr, nullptr);
  k_lstm<<<(NN * 64) / 256, 256, 0, stream>>>(
      gates, c_full + 0, nid, hs_out, cs_out, bufA, nullptr, nullptr, nullptr);
  // layer 1: gates = [h_new0, h0_1] @ Wt1
  k_linear<128, 64, 256, 64, false><<<GB_LIN, 256, 0, stream>>>(
      bufA, h_full + (size_t)NN * 64, nid, Wt1, bih1, bhh1, nullptr, nullptr, gates, nullptr, nullptr);
  k_lstm<<<(NN * 64) / 256, 256, 0, stream>>>(
      gates, c_full + (size_t)NN * 64, nid,
      hs_out + (size_t)NN * 64, cs_out + (size_t)NN * 64, nullptr, outW, outb, pred_out);
}